// Round 1
// 984.824 us; speedup vs baseline: 1.5648x; 1.5648x over previous
//
#include <hip/hip_runtime.h>
#include <hip/hip_bf16.h>

#define BB 4
#define NN 4096
#define DD 256
#define RR 64
#define KK 16
#define TM 16   // rows per projection block

typedef __attribute__((ext_vector_type(8))) short bf16x8;
typedef __attribute__((ext_vector_type(4))) float f32x4;

__device__ __forceinline__ void f32_split(float x, ushort* h, ushort* l){
  __hip_bfloat16 hb = __float2bfloat16(x);
  float hf = __bfloat162float(hb);
  __hip_bfloat16 lb = __float2bfloat16(x - hf);
  *h = *(ushort*)&hb; *l = *(ushort*)&lb;
}

// ---------------- signed softmax over 4096 (block per row) ----------------
__global__ void __launch_bounds__(256) ssm_kernel(
    const float* __restrict__ xf, long xf_stride,
    const float* __restrict__ add, long add_stride,
    float* __restrict__ outf, long outf_stride)
{
  __shared__ float sm[8];
  int t = threadIdx.x;
  long b = blockIdx.x;
  float x[16]; float mx = 0.f;
  #pragma unroll
  for (int j=0;j<16;j++){
    int i = t + j*256;
    float v = xf[b*xf_stride + i];
    if (add) v += add[b*add_stride + i];
    x[j]=v; mx = fmaxf(mx, fabsf(v));
  }
  #pragma unroll
  for (int o=1;o<64;o<<=1) mx = fmaxf(mx, __shfl_xor(mx,o,64));
  int wid = t>>6;
  if ((t&63)==0) sm[wid]=mx;
  __syncthreads();
  mx = fmaxf(fmaxf(sm[0],sm[1]), fmaxf(sm[2],sm[3]));
  float e[16]; float ssum=0.f;
  #pragma unroll
  for (int j=0;j<16;j++){ e[j]=expf(fabsf(x[j])-mx); ssum+=e[j]; }
  #pragma unroll
  for (int o=1;o<64;o<<=1) ssum += __shfl_xor(ssum,o,64);
  if ((t&63)==0) sm[4+wid]=ssum;
  __syncthreads();
  ssum = sm[4]+sm[5]+sm[6]+sm[7];
  float inv = 1.0f/ssum;
  #pragma unroll
  for (int j=0;j<16;j++){
    int i = t + j*256;
    float sg = (x[j]>0.f)?1.f:((x[j]<0.f)?-1.f:0.f);
    outf[b*outf_stride + i] = sg*e[j]*inv;
  }
}

// ------ projection with 0/1/2 inline layernorms: out = ln^nln(src) @ [U|V] ------
// Optionally also writes the normalized rows (NV) and per-row 1/(||x||+1e-6)
// (NRM) so gather_kernel never re-does per-message LN / norm reductions.
__global__ void __launch_bounds__(256) proj_ln_kernel(
    const float* __restrict__ src,
    const float* __restrict__ lg, const float* __restrict__ lb, int nln,
    const float* __restrict__ U, ushort* __restrict__ oUh, ushort* __restrict__ oUl, float scaleU,
    const float* __restrict__ V, ushort* __restrict__ oVh, ushort* __restrict__ oVl, float scaleV,
    float* __restrict__ nvout, float* __restrict__ nrmout)
{
  __shared__ float xs[TM][DD];     // 16 KB
  __shared__ float ut[64*64];      // 16 KB
  __shared__ float vt[64*64];      // 16 KB
  int t = threadIdx.x;
  int wid = t>>6, lane = t&63;
  long row0 = (long)blockIdx.x*TM;

  float gv[4], bv[4];
  if (nln){
    #pragma unroll
    for (int u=0;u<4;u++){ int d=u*64+lane; gv[u]=lg[d]; bv[u]=lb[d]; }
  }
  for (int rr=0; rr<4; rr++){
    int r = wid*4 + rr;
    const float* srow = src + (row0 + r)*DD;
    float x[4];
    #pragma unroll
    for (int u=0;u<4;u++) x[u] = srow[u*64 + lane];
    for (int p=0;p<nln;p++){
      float s=0.f,q=0.f;
      #pragma unroll
      for (int u=0;u<4;u++){ s+=x[u]; q+=x[u]*x[u]; }
      #pragma unroll
      for (int o=1;o<64;o<<=1){ s+=__shfl_xor(s,o,64); q+=__shfl_xor(q,o,64); }
      float m = s*(1.f/DD), var = q*(1.f/DD)-m*m, rstd = rsqrtf(var+1e-5f);
      #pragma unroll
      for (int u=0;u<4;u++) x[u] = (x[u]-m)*rstd*gv[u]+bv[u];
    }
    if (nrmout){
      float ss=0.f;
      #pragma unroll
      for (int u=0;u<4;u++) ss += x[u]*x[u];
      #pragma unroll
      for (int o=1;o<64;o<<=1) ss += __shfl_xor(ss,o,64);
      if (lane==0) nrmout[row0 + r] = 1.f/(sqrtf(ss)+1e-6f);
    }
    if (nvout){
      #pragma unroll
      for (int u=0;u<4;u++) nvout[(row0 + r)*DD + u*64 + lane] = x[u];
    }
    #pragma unroll
    for (int u=0;u<4;u++) xs[r][u*64+lane] = x[u];
  }
  __syncthreads();

  float aU[4] = {0.f,0.f,0.f,0.f};
  float aV[4] = {0.f,0.f,0.f,0.f};
  for (int kt=0; kt<4; kt++){
    const float4* Ut = (const float4*)(U + (long)kt*64*RR);
    #pragma unroll
    for (int i=0;i<4;i++) ((float4*)ut)[i*256 + t] = Ut[i*256 + t];
    if (V){
      const float4* Vt = (const float4*)(V + (long)kt*64*RR);
      #pragma unroll
      for (int i=0;i<4;i++) ((float4*)vt)[i*256 + t] = Vt[i*256 + t];
    }
    __syncthreads();
    #pragma unroll 4
    for (int dd=0; dd<64; dd+=4){
      float4 xq[4];
      #pragma unroll
      for (int r=0;r<4;r++) xq[r] = *(const float4*)&xs[wid*4+r][kt*64+dd];
      #pragma unroll
      for (int j=0;j<4;j++){
        float uv = ut[(dd+j)*64 + lane];
        float vv = V ? vt[(dd+j)*64 + lane] : 0.f;
        #pragma unroll
        for (int r=0;r<4;r++){
          float xv = (j==0)?xq[r].x:(j==1)?xq[r].y:(j==2)?xq[r].z:xq[r].w;
          aU[r] += xv*uv;
          if (V) aV[r] += xv*vv;
        }
      }
    }
    __syncthreads();
  }
  #pragma unroll
  for (int r=0;r<4;r++){
    long row = row0 + wid*4 + r;
    ushort h, l;
    f32_split(aU[r]*scaleU, &h, &l);
    oUh[row*RR + lane] = h; oUl[row*RR + lane] = l;
    if (V){
      f32_split(aV[r]*scaleV, &h, &l);
      oVh[row*RR + lane] = h; oVl[row*RR + lane] = l;
    }
  }
}

// ---- MFMA score GEMM: C[i,j] = dot(dp[i],sp[j]) via bf16 hi/lo 3-pass split ----
// Block = 4 waves (2x2), wave computes 64x64. Tile 128(dst) x 128(src).
__global__ void __launch_bounds__(256) score_mfma(
    const ushort* __restrict__ dph, const ushort* __restrict__ dpl, long dp_bs,
    const ushort* __restrict__ sph, const ushort* __restrict__ spl,
    float* __restrict__ scores, int n0, int cr)
{
  int b = blockIdx.z;
  int t = threadIdx.x;
  int w = t >> 6, lane = t & 63;
  int wr = w >> 1, wc = w & 1;
  int row16 = lane & 15;
  int quad  = lane >> 4;
  long dst0 = (long)n0 + blockIdx.y*128 + wr*64;
  long src0 = (long)blockIdx.x*128 + wc*64;
  const ushort* Ah = dph + (long)b*dp_bs + (dst0 + row16)*RR + quad*8;
  const ushort* Al = dpl + (long)b*dp_bs + (dst0 + row16)*RR + quad*8;
  const ushort* Bh = sph + (long)b*NN*RR + (src0 + row16)*RR + quad*8;
  const ushort* Bl = spl + (long)b*NN*RR + (src0 + row16)*RR + quad*8;
  f32x4 acc[4][4];
  #pragma unroll
  for (int mi=0;mi<4;mi++)
    #pragma unroll
    for (int ni=0;ni<4;ni++) acc[mi][ni] = (f32x4){0.f,0.f,0.f,0.f};
  #pragma unroll
  for (int s=0; s<2; s++){
    bf16x8 ah[4], al[4], bh[4], bl[4];
    #pragma unroll
    for (int mi=0;mi<4;mi++){
      ah[mi] = *(const bf16x8*)(Ah + (long)mi*16*RR + s*32);
      al[mi] = *(const bf16x8*)(Al + (long)mi*16*RR + s*32);
    }
    #pragma unroll
    for (int ni=0;ni<4;ni++){
      bh[ni] = *(const bf16x8*)(Bh + (long)ni*16*RR + s*32);
      bl[ni] = *(const bf16x8*)(Bl + (long)ni*16*RR + s*32);
    }
    #pragma unroll
    for (int mi=0;mi<4;mi++){
      #pragma unroll
      for (int ni=0;ni<4;ni++){
        acc[mi][ni] = __builtin_amdgcn_mfma_f32_16x16x32_bf16(ah[mi], bh[ni], acc[mi][ni], 0,0,0);
        acc[mi][ni] = __builtin_amdgcn_mfma_f32_16x16x32_bf16(ah[mi], bl[ni], acc[mi][ni], 0,0,0);
        acc[mi][ni] = __builtin_amdgcn_mfma_f32_16x16x32_bf16(al[mi], bh[ni], acc[mi][ni], 0,0,0);
      }
    }
  }
  // C/D layout: col = lane&15, row = quad*4 + reg  [m89/m91 verified]
  long crow0 = (long)b*cr + (dst0 - n0);
  #pragma unroll
  for (int mi=0;mi<4;mi++){
    #pragma unroll
    for (int ni=0;ni<4;ni++){
      #pragma unroll
      for (int reg=0;reg<4;reg++){
        long r = crow0 + mi*16 + quad*4 + reg;
        scores[r*NN + src0 + ni*16 + row16] = acc[mi][ni][reg];
      }
    }
  }
}

// -------- top-16 by |score| over 4096 (one wave per row) --------
// v2: exact threshold pruning. T = 16th-largest of the 64 per-lane maxes is a
// provable lower bound on the 16th-largest |value| (16 lanes have max >= T and
// each lane-max IS a value => >=16 values >= T => V16 >= T). Candidates >= T
// (typically ~30-60) are compacted to LDS and the 16 extractions run over
// <=128 candidates with all lanes busy, instead of the old 16 x 64-element
// single-lane diverged rescan. Rows with >128 candidates (degenerate ties)
// take the verbatim old path — selection is bit-identical either way.
__global__ void __launch_bounds__(256) topk_kernel(
    const float* __restrict__ scores,
    float* __restrict__ wout, int* __restrict__ iout,
    int n0, int cr)
{
  __shared__ float candV[4][128];
  __shared__ int   candI[4][128];
  int wid  = threadIdx.x >> 6;
  int lane = threadIdx.x & 63;
  int g = blockIdx.x*4 + wid;
  int b = g / cr;
  int i = g - b*cr;
  const float* s = scores + ((long)b*cr + i)*NN;
  float v[64];
  #pragma unroll
  for (int q=0;q<16;q++)
    *(float4*)&v[q*4] = *(const float4*)(s + lane*64 + q*4);

  float lm = 0.f;
  #pragma unroll
  for (int j=0;j<64;j++) lm = fmaxf(lm, fabsf(v[j]));

  // T = 16th largest of the 64 lane-maxes (keys only, one removal per round)
  float cur = lm, T = 0.f;
  for (int t=0;t<16;t++){
    float m = cur;
    #pragma unroll
    for (int o=1;o<64;o<<=1) m = fmaxf(m, __shfl_xor(m,o,64));
    T = m;
    unsigned long long msk = __ballot(cur == m);
    int low = __ffsll(msk) - 1;
    if (lane == low) cur = -1.f;
  }

  int cnt = 0;
  #pragma unroll
  for (int j=0;j<64;j++) cnt += (fabsf(v[j]) >= T) ? 1 : 0;
  int xs = cnt;
  #pragma unroll
  for (int o=1;o<64;o<<=1){ int y=__shfl_up(xs,o,64); if (lane>=o) xs+=y; }
  int tot = __shfl(xs,63,64);
  bool fast = (tot <= 128);
  if (fast){
    candV[wid][lane]=0.f;        candV[wid][lane+64]=0.f;
    candI[wid][lane]=0x7fffffff; candI[wid][lane+64]=0x7fffffff;
    int p = xs - cnt;
    #pragma unroll
    for (int j=0;j<64;j++){
      if (fabsf(v[j]) >= T){ candV[wid][p]=v[j]; candI[wid][p]=lane*64+j; p++; }
    }
  }
  __syncthreads();   // uniform: all waves reach regardless of fast/slow
  long orow = ((long)b*NN + n0 + i)*KK;
  if (fast){
    float cv0=candV[wid][lane], cv1=candV[wid][lane+64];
    int   ci0=candI[wid][lane], ci1=candI[wid][lane+64];
    float k0=fabsf(cv0), k1=fabsf(cv1);
    bool f0=(ci0==0x7fffffff), f1=(ci1==0x7fffffff);
    for (int t=0;t<KK;t++){
      float bk; int bgi; float bv;
      bool pick0 = !f0 && (f1 || k0>k1 || (k0==k1 && ci0<ci1));
      if (pick0){ bk=k0; bgi=ci0; bv=cv0; }
      else if (!f1){ bk=k1; bgi=ci1; bv=cv1; }
      else { bk=-1.f; bgi=0x7fffffff; bv=0.f; }
      #pragma unroll
      for (int o=1;o<64;o<<=1){
        float ko=__shfl_xor(bk,o,64);
        int  gio=__shfl_xor(bgi,o,64);
        float vo=__shfl_xor(bv,o,64);
        if (ko>bk || (ko==bk && gio<bgi)){ bk=ko; bgi=gio; bv=vo; }
      }
      if (lane==0){ wout[orow+t]=bv; iout[orow+t]=bgi; }
      if (!f0 && bgi==ci0) f0=true;
      else if (!f1 && bgi==ci1) f1=true;
    }
  } else {
    unsigned long long cons = 0ull;
    float bk=-1.f, bval=0.f; int bj=0;
    #pragma unroll
    for (int j=0;j<64;j++){
      float k = fabsf(v[j]);
      if (k > bk){ bk=k; bj=j; bval=v[j]; }
    }
    for (int t=0;t<KK;t++){
      float k = bk; int gi = lane*64 + bj; float val = bval;
      #pragma unroll
      for (int o=1;o<64;o<<=1){
        float ko = __shfl_xor(k,o,64);
        int  gio = __shfl_xor(gi,o,64);
        float vo = __shfl_xor(val,o,64);
        if (ko > k || (ko == k && gio < gi)){ k=ko; gi=gio; val=vo; }
      }
      if (lane == 0){ wout[orow+t]=val; iout[orow+t]=gi; }
      if (lane == (gi>>6)){
        cons |= 1ull << (gi & 63);
        bk=-1.f; bj=0; bval=0.f;
        #pragma unroll
        for (int j=0;j<64;j++){
          if (!((cons>>j)&1ull)){
            float kk=fabsf(v[j]);
            if (kk>bk){ bk=kk; bj=j; bval=v[j]; }
          }
        }
      }
    }
  }
}

// ---- gather + signed-softmax weights + fused apply_delta ----
// v2: per-message LN + norm hoisted to proj_ln (NV/NRM buffers); phase 1 is
// now a float4 copy + one scalar invn load per message.
__global__ void __launch_bounds__(256) gather_kernel(
    const float* __restrict__ wbuf, const int* __restrict__ ibuf,
    const float* __restrict__ sv, long sv_bs,
    const float* __restrict__ nrm,
    const float* __restrict__ st, long st_bs,
    const float* __restrict__ base, int base_mod,
    const float* __restrict__ bg, const float* __restrict__ bb,
    const float* __restrict__ og, const float* __restrict__ ob,
    float* __restrict__ outv, float* __restrict__ ds)
{
  __shared__ float msg[KK][DD+4];
  __shared__ float wts[KK], invn[KK];
  __shared__ int sidx[KK];
  __shared__ float sm[8];
  long row = blockIdx.x;
  int b = (int)(row >> 12);
  int t = threadIdx.x;
  int wid = t>>6, lane = t&63;
  if (t < KK) sidx[t] = ibuf[row*KK + t];
  __syncthreads();
  for (int k=wid; k<KK; k+=4){
    int si = sidx[k];
    long sr = (long)b*sv_bs + (long)si*DD;
    float4 q = *(const float4*)(sv + sr + lane*4);
    *(float4*)&msg[k][lane*4] = q;
    if (lane==0) invn[k] = nrm[(long)b*NN + si];
  }
  __syncthreads();
  if (t < KK){
    const float* wr = wbuf + row*KK;
    float m=0.f;
    for (int k=0;k<KK;k++) m = fmaxf(m, fabsf(wr[k]));
    float Z=0.f;
    for (int k=0;k<KK;k++) Z += expf(fabsf(wr[k])-m);
    float x = wr[t];
    float sg = (x>0.f)?1.f:((x<0.f)?-1.f:0.f);
    float vv = sg*expf(fabsf(x)-m)/Z;
    if (st){
      float stv = st[(long)b*st_bs + sidx[t]];
      vv *= fmaxf(stv,0.f) + log1pf(expf(-fabsf(stv)));   // softplus
    }
    wts[t]=vv;
  }
  __syncthreads();
  float acc=0.f;
  #pragma unroll
  for (int k=0;k<KK;k++) acc += wts[k]*invn[k]*msg[k][t];
  if (t==0){
    float sum=0.f;
    #pragma unroll
    for (int k=0;k<KK;k++) sum += wts[k];
    ds[row] = sum;
  }
  if (!base){
    outv[row*DD + t] = acc;
    return;
  }
  float x = base[(long)(base_mod ? (row % base_mod) : row)*DD + t];
  if (bg){
    float s=x, q=x*x;
    #pragma unroll
    for (int o=1;o<64;o<<=1){ s+=__shfl_xor(s,o,64); q+=__shfl_xor(q,o,64); }
    if (lane==0){ sm[wid]=s; sm[4+wid]=q; }
    __syncthreads();
    float S = sm[0]+sm[1]+sm[2]+sm[3];
    float Q = sm[4]+sm[5]+sm[6]+sm[7];
    float m=S*(1.f/DD), var=Q*(1.f/DD)-m*m, rstd=rsqrtf(var+1e-5f);
    x = (x-m)*rstd*bg[t] + bb[t];
    __syncthreads();
  }
  x += acc;
  {
    float s=x, q=x*x;
    #pragma unroll
    for (int o=1;o<64;o<<=1){ s+=__shfl_xor(s,o,64); q+=__shfl_xor(q,o,64); }
    if (lane==0){ sm[wid]=s; sm[4+wid]=q; }
    __syncthreads();
    float S = sm[0]+sm[1]+sm[2]+sm[3];
    float Q = sm[4]+sm[5]+sm[6]+sm[7];
    float m=S*(1.f/DD), var=Q*(1.f/DD)-m*m, rstd=rsqrtf(var+1e-5f);
    outv[row*DD + t] = (x-m)*rstd*og[t] + ob[t];
  }
}

extern "C" void kernel_launch(void* const* d_in, const int* in_sizes, int n_in,
                              void* d_out, int out_size, void* d_ws, size_t ws_size,
                              hipStream_t stream)
{
  const float* b_state    = (const float*)d_in[0];
  const float* b_val      = (const float*)d_in[1];
  const float* init_state = (const float*)d_in[2];
  const float* init_val   = (const float*)d_in[3];
  const float* U_bk = (const float*)d_in[4];
  const float* V_bk = (const float*)d_in[5];
  const float* U_kb = (const float*)d_in[6];
  const float* V_kb = (const float*)d_in[7];
  const float* U_p  = (const float*)d_in[8];
  const float* V_p  = (const float*)d_in[9];
  const float* kn_g = (const float*)d_in[10];
  const float* kn_b = (const float*)d_in[11];
  const float* bn_g = (const float*)d_in[12];
  const float* bn_b = (const float*)d_in[13];
  const float* pn_g = (const float*)d_in[14];
  const float* pn_b = (const float*)d_in[15];
  float* out = (float*)d_out;

  const long o_rstate = 0;
  const long o_rval   = (long)BB*NN;
  const long o_pstate = o_rval + (long)BB*NN*DD;
  const long o_pval   = o_pstate + (long)BB*NN;
  const long o_bds    = o_pval + (long)BB*NN*DD;
  const long o_bdv    = o_bds + (long)BB*NN;

  float* RVAL = out + o_rval;
  float* PVAL = out + o_pval;
  float* RST  = out + o_rstate;
  float* PST  = out + o_pstate;

  ushort* SPh = (ushort*)d_ws;                   // [B,N,R] bf16 hi
  ushort* SPl = SPh + (long)BB*NN*RR;
  ushort* DPh = SPl + (long)BB*NN*RR;
  ushort* DPl = DPh + (long)BB*NN*RR;
  float* WB   = (float*)(DPl + (long)BB*NN*RR);  // [B,N,K]
  int*   IB   = (int*)(WB + (long)BB*NN*KK);     // [B,N,K]
  float* KST  = (float*)(IB + (long)BB*NN*KK);   // [N]
  float* DS   = KST + NN;                        // [B,N]
  float* NV   = DS + (long)BB*NN;                // [B,N,D] normalized msgs
  float* NRM  = NV + (long)BB*NN*DD;             // [B,N] 1/(||row||+1e-6)
  float* SC   = NRM + (long)BB*NN;               // [B,cr,N] score chunk
  long fixed_bytes = (char*)SC - (char*)d_ws;
  int cr = 2048;
  while (cr > 128 && fixed_bytes + (long)BB*cr*NN*4 > (long)ws_size) cr >>= 1;

  auto run_scores = [&](const ushort* dh, const ushort* dl, long dpbs,
                        const ushort* sh, const ushort* sl){
    int nch = NN / cr;
    for (int c=0;c<nch;c++){
      score_mfma<<<dim3(NN/128, cr/128, BB), 256, 0, stream>>>(dh, dl, dpbs, sh, sl, SC, c*cr, cr);
      topk_kernel<<<dim3(BB*cr/4), 256, 0, stream>>>(SC, WB, IB, c*cr, cr);
    }
  };

  // ---- initialize_state: k_state (batch-independent) ----
  ssm_kernel<<<1,256,0,stream>>>(init_state, 0, nullptr, 0, KST, 0);

  // ---- route_from_b: B -> K ----
  proj_ln_kernel<<<NN/TM,256,0,stream>>>(init_val, kn_g, kn_b, 2,
                                         V_bk, DPh, DPl, 0.125f, nullptr, nullptr, nullptr, 0.f,
                                         nullptr, nullptr);
  proj_ln_kernel<<<BB*NN/TM,256,0,stream>>>(b_val, nullptr, nullptr, 0,
                                            U_bk, SPh, SPl, 1.0f, nullptr, nullptr, nullptr, 0.f,
                                            nullptr, NRM);
  run_scores(DPh, DPl, 0, SPh, SPl);
  gather_kernel<<<BB*NN,256,0,stream>>>(WB, IB,
      b_val, (long)NN*DD, NRM,
      b_state, (long)NN,
      init_val, NN, kn_g, kn_b, kn_g, kn_b,
      RVAL, DS);
  ssm_kernel<<<BB,256,0,stream>>>(KST, 0, DS, NN, RST, NN);

  // ---- propagate ----
  proj_ln_kernel<<<BB*NN/TM,256,0,stream>>>(RVAL, pn_g, pn_b, 1,
                                            U_p, SPh, SPl, 1.0f, V_p, DPh, DPl, 0.125f,
                                            NV, NRM);
  run_scores(DPh, DPl, (long)NN*RR, SPh, SPl);
  gather_kernel<<<BB*NN,256,0,stream>>>(WB, IB,
      NV, (long)NN*DD, NRM,
      nullptr, 0,
      RVAL, 0, nullptr, nullptr, kn_g, kn_b,
      PVAL, DS);
  ssm_kernel<<<BB,256,0,stream>>>(RST, NN, DS, NN, PST, NN);

  // ---- transition_to_b: K -> B ----
  proj_ln_kernel<<<BB*NN/TM,256,0,stream>>>(PVAL, kn_g, kn_b, 1,
                                            U_kb, SPh, SPl, 1.0f, nullptr, nullptr, nullptr, 0.f,
                                            NV, NRM);
  proj_ln_kernel<<<BB*NN/TM,256,0,stream>>>(b_val, bn_g, bn_b, 1,
                                            V_kb, DPh, DPl, 0.125f, nullptr, nullptr, nullptr, 0.f,
                                            nullptr, nullptr);
  run_scores(DPh, DPl, (long)NN*RR, SPh, SPl);
  gather_kernel<<<BB*NN,256,0,stream>>>(WB, IB,
      NV, (long)NN*DD, NRM,
      PST, (long)NN,
      nullptr, 0, nullptr, nullptr, nullptr, nullptr,
      out + o_bdv, out + o_bds);
}

// Round 2
// 891.329 us; speedup vs baseline: 1.7290x; 1.1049x over previous
//
#include <hip/hip_runtime.h>
#include <hip/hip_bf16.h>

#define BB 4
#define NN 4096
#define DD 256
#define RR 64
#define KK 16
#define TM 16   // rows per projection block

typedef __attribute__((ext_vector_type(8))) short bf16x8;
typedef __attribute__((ext_vector_type(4))) float f32x4;

__device__ __forceinline__ void f32_split(float x, ushort* h, ushort* l){
  __hip_bfloat16 hb = __float2bfloat16(x);
  float hf = __bfloat162float(hb);
  __hip_bfloat16 lb = __float2bfloat16(x - hf);
  *h = *(ushort*)&hb; *l = *(ushort*)&lb;
}

// ---------------- signed softmax over 4096 (block per row, 1024 thr) ----------------
__global__ void __launch_bounds__(1024) ssm_kernel(
    const float* __restrict__ xf, long xf_stride,
    const float* __restrict__ add, long add_stride,
    float* __restrict__ outf, long outf_stride)
{
  __shared__ float sm[32];
  int t = threadIdx.x;
  long b = blockIdx.x;
  float x[4]; float mx = 0.f;
  #pragma unroll
  for (int j=0;j<4;j++){
    int i = t + j*1024;
    float v = xf[b*xf_stride + i];
    if (add) v += add[b*add_stride + i];
    x[j]=v; mx = fmaxf(mx, fabsf(v));
  }
  #pragma unroll
  for (int o=1;o<64;o<<=1) mx = fmaxf(mx, __shfl_xor(mx,o,64));
  int wid = t>>6;
  if ((t&63)==0) sm[wid]=mx;
  __syncthreads();
  mx = sm[0];
  #pragma unroll
  for (int w=1;w<16;w++) mx = fmaxf(mx, sm[w]);
  float e[4]; float ssum=0.f;
  #pragma unroll
  for (int j=0;j<4;j++){ e[j]=expf(fabsf(x[j])-mx); ssum+=e[j]; }
  #pragma unroll
  for (int o=1;o<64;o<<=1) ssum += __shfl_xor(ssum,o,64);
  if ((t&63)==0) sm[16+wid]=ssum;
  __syncthreads();
  ssum = sm[16];
  #pragma unroll
  for (int w=1;w<16;w++) ssum += sm[16+w];
  float inv = 1.0f/ssum;
  #pragma unroll
  for (int j=0;j<4;j++){
    int i = t + j*1024;
    float sg = (x[j]>0.f)?1.f:((x[j]<0.f)?-1.f:0.f);
    outf[b*outf_stride + i] = sg*e[j]*inv;
  }
}

// ------ projection with 0/1/2 inline layernorms: out = ln^nln(src) @ [U|V] ------
// Optionally also writes the normalized rows (NV) and per-row 1/(||x||+1e-6)
// (NRM) so gather_kernel never re-does per-message LN / norm reductions.
__global__ void __launch_bounds__(256) proj_ln_kernel(
    const float* __restrict__ src,
    const float* __restrict__ lg, const float* __restrict__ lb, int nln,
    const float* __restrict__ U, ushort* __restrict__ oUh, ushort* __restrict__ oUl, float scaleU,
    const float* __restrict__ V, ushort* __restrict__ oVh, ushort* __restrict__ oVl, float scaleV,
    float* __restrict__ nvout, float* __restrict__ nrmout)
{
  __shared__ float xs[TM][DD];     // 16 KB
  __shared__ float ut[64*64];      // 16 KB
  __shared__ float vt[64*64];      // 16 KB
  int t = threadIdx.x;
  int wid = t>>6, lane = t&63;
  long row0 = (long)blockIdx.x*TM;

  float gv[4], bv[4];
  if (nln){
    #pragma unroll
    for (int u=0;u<4;u++){ int d=u*64+lane; gv[u]=lg[d]; bv[u]=lb[d]; }
  }
  for (int rr=0; rr<4; rr++){
    int r = wid*4 + rr;
    const float* srow = src + (row0 + r)*DD;
    float x[4];
    #pragma unroll
    for (int u=0;u<4;u++) x[u] = srow[u*64 + lane];
    for (int p=0;p<nln;p++){
      float s=0.f,q=0.f;
      #pragma unroll
      for (int u=0;u<4;u++){ s+=x[u]; q+=x[u]*x[u]; }
      #pragma unroll
      for (int o=1;o<64;o<<=1){ s+=__shfl_xor(s,o,64); q+=__shfl_xor(q,o,64); }
      float m = s*(1.f/DD), var = q*(1.f/DD)-m*m, rstd = rsqrtf(var+1e-5f);
      #pragma unroll
      for (int u=0;u<4;u++) x[u] = (x[u]-m)*rstd*gv[u]+bv[u];
    }
    if (nrmout){
      float ss=0.f;
      #pragma unroll
      for (int u=0;u<4;u++) ss += x[u]*x[u];
      #pragma unroll
      for (int o=1;o<64;o<<=1) ss += __shfl_xor(ss,o,64);
      if (lane==0) nrmout[row0 + r] = 1.f/(sqrtf(ss)+1e-6f);
    }
    if (nvout){
      #pragma unroll
      for (int u=0;u<4;u++) nvout[(row0 + r)*DD + u*64 + lane] = x[u];
    }
    #pragma unroll
    for (int u=0;u<4;u++) xs[r][u*64+lane] = x[u];
  }
  __syncthreads();

  float aU[4] = {0.f,0.f,0.f,0.f};
  float aV[4] = {0.f,0.f,0.f,0.f};
  for (int kt=0; kt<4; kt++){
    const float4* Ut = (const float4*)(U + (long)kt*64*RR);
    #pragma unroll
    for (int i=0;i<4;i++) ((float4*)ut)[i*256 + t] = Ut[i*256 + t];
    if (V){
      const float4* Vt = (const float4*)(V + (long)kt*64*RR);
      #pragma unroll
      for (int i=0;i<4;i++) ((float4*)vt)[i*256 + t] = Vt[i*256 + t];
    }
    __syncthreads();
    #pragma unroll 4
    for (int dd=0; dd<64; dd+=4){
      float4 xq[4];
      #pragma unroll
      for (int r=0;r<4;r++) xq[r] = *(const float4*)&xs[wid*4+r][kt*64+dd];
      #pragma unroll
      for (int j=0;j<4;j++){
        float uv = ut[(dd+j)*64 + lane];
        float vv = V ? vt[(dd+j)*64 + lane] : 0.f;
        #pragma unroll
        for (int r=0;r<4;r++){
          float xv = (j==0)?xq[r].x:(j==1)?xq[r].y:(j==2)?xq[r].z:xq[r].w;
          aU[r] += xv*uv;
          if (V) aV[r] += xv*vv;
        }
      }
    }
    __syncthreads();
  }
  #pragma unroll
  for (int r=0;r<4;r++){
    long row = row0 + wid*4 + r;
    ushort h, l;
    f32_split(aU[r]*scaleU, &h, &l);
    oUh[row*RR + lane] = h; oUl[row*RR + lane] = l;
    if (V){
      f32_split(aV[r]*scaleV, &h, &l);
      oVh[row*RR + lane] = h; oVl[row*RR + lane] = l;
    }
  }
}

// ---- MFMA score GEMM: C[i,j] = dot(dp[i],sp[j]) via bf16 hi/lo 3-pass split ----
// Block = 4 waves (2x2), wave computes 64x64. Tile 128(dst) x 128(src).
__global__ void __launch_bounds__(256) score_mfma(
    const ushort* __restrict__ dph, const ushort* __restrict__ dpl, long dp_bs,
    const ushort* __restrict__ sph, const ushort* __restrict__ spl,
    float* __restrict__ scores, int n0, int cr)
{
  int b = blockIdx.z;
  int t = threadIdx.x;
  int w = t >> 6, lane = t & 63;
  int wr = w >> 1, wc = w & 1;
  int row16 = lane & 15;
  int quad  = lane >> 4;
  long dst0 = (long)n0 + blockIdx.y*128 + wr*64;
  long src0 = (long)blockIdx.x*128 + wc*64;
  const ushort* Ah = dph + (long)b*dp_bs + (dst0 + row16)*RR + quad*8;
  const ushort* Al = dpl + (long)b*dp_bs + (dst0 + row16)*RR + quad*8;
  const ushort* Bh = sph + (long)b*NN*RR + (src0 + row16)*RR + quad*8;
  const ushort* Bl = spl + (long)b*NN*RR + (src0 + row16)*RR + quad*8;
  f32x4 acc[4][4];
  #pragma unroll
  for (int mi=0;mi<4;mi++)
    #pragma unroll
    for (int ni=0;ni<4;ni++) acc[mi][ni] = (f32x4){0.f,0.f,0.f,0.f};
  #pragma unroll
  for (int s=0; s<2; s++){
    bf16x8 ah[4], al[4], bh[4], bl[4];
    #pragma unroll
    for (int mi=0;mi<4;mi++){
      ah[mi] = *(const bf16x8*)(Ah + (long)mi*16*RR + s*32);
      al[mi] = *(const bf16x8*)(Al + (long)mi*16*RR + s*32);
    }
    #pragma unroll
    for (int ni=0;ni<4;ni++){
      bh[ni] = *(const bf16x8*)(Bh + (long)ni*16*RR + s*32);
      bl[ni] = *(const bf16x8*)(Bl + (long)ni*16*RR + s*32);
    }
    #pragma unroll
    for (int mi=0;mi<4;mi++){
      #pragma unroll
      for (int ni=0;ni<4;ni++){
        acc[mi][ni] = __builtin_amdgcn_mfma_f32_16x16x32_bf16(ah[mi], bh[ni], acc[mi][ni], 0,0,0);
        acc[mi][ni] = __builtin_amdgcn_mfma_f32_16x16x32_bf16(ah[mi], bl[ni], acc[mi][ni], 0,0,0);
        acc[mi][ni] = __builtin_amdgcn_mfma_f32_16x16x32_bf16(al[mi], bh[ni], acc[mi][ni], 0,0,0);
      }
    }
  }
  // C/D layout: col = lane&15, row = quad*4 + reg  [m89/m91 verified]
  long crow0 = (long)b*cr + (dst0 - n0);
  #pragma unroll
  for (int mi=0;mi<4;mi++){
    #pragma unroll
    for (int ni=0;ni<4;ni++){
      #pragma unroll
      for (int reg=0;reg<4;reg++){
        long r = crow0 + mi*16 + quad*4 + reg;
        scores[r*NN + src0 + ni*16 + row16] = acc[mi][ni][reg];
      }
    }
  }
}

// -------- top-16 by |score| over 4096 (one wave per row) --------
// v2: exact threshold pruning. T = 16th-largest of the 64 per-lane maxes is a
// provable lower bound on the 16th-largest |value|. Candidates >= T are
// compacted to LDS and the 16 extractions run over <=128 candidates with all
// lanes busy. Rows with >128 candidates take the verbatim old path —
// selection is bit-identical either way.
__global__ void __launch_bounds__(256) topk_kernel(
    const float* __restrict__ scores,
    float* __restrict__ wout, int* __restrict__ iout,
    int n0, int cr)
{
  __shared__ float candV[4][128];
  __shared__ int   candI[4][128];
  int wid  = threadIdx.x >> 6;
  int lane = threadIdx.x & 63;
  int g = blockIdx.x*4 + wid;
  int b = g / cr;
  int i = g - b*cr;
  const float* s = scores + ((long)b*cr + i)*NN;
  float v[64];
  #pragma unroll
  for (int q=0;q<16;q++)
    *(float4*)&v[q*4] = *(const float4*)(s + lane*64 + q*4);

  float lm = 0.f;
  #pragma unroll
  for (int j=0;j<64;j++) lm = fmaxf(lm, fabsf(v[j]));

  // T = 16th largest of the 64 lane-maxes (keys only, one removal per round)
  float cur = lm, T = 0.f;
  for (int t=0;t<16;t++){
    float m = cur;
    #pragma unroll
    for (int o=1;o<64;o<<=1) m = fmaxf(m, __shfl_xor(m,o,64));
    T = m;
    unsigned long long msk = __ballot(cur == m);
    int low = __ffsll(msk) - 1;
    if (lane == low) cur = -1.f;
  }

  int cnt = 0;
  #pragma unroll
  for (int j=0;j<64;j++) cnt += (fabsf(v[j]) >= T) ? 1 : 0;
  int xs = cnt;
  #pragma unroll
  for (int o=1;o<64;o<<=1){ int y=__shfl_up(xs,o,64); if (lane>=o) xs+=y; }
  int tot = __shfl(xs,63,64);
  bool fast = (tot <= 128);
  if (fast){
    candV[wid][lane]=0.f;        candV[wid][lane+64]=0.f;
    candI[wid][lane]=0x7fffffff; candI[wid][lane+64]=0x7fffffff;
    int p = xs - cnt;
    #pragma unroll
    for (int j=0;j<64;j++){
      if (fabsf(v[j]) >= T){ candV[wid][p]=v[j]; candI[wid][p]=lane*64+j; p++; }
    }
  }
  __syncthreads();   // uniform: all waves reach regardless of fast/slow
  long orow = ((long)b*NN + n0 + i)*KK;
  if (fast){
    float cv0=candV[wid][lane], cv1=candV[wid][lane+64];
    int   ci0=candI[wid][lane], ci1=candI[wid][lane+64];
    float k0=fabsf(cv0), k1=fabsf(cv1);
    bool f0=(ci0==0x7fffffff), f1=(ci1==0x7fffffff);
    for (int t=0;t<KK;t++){
      float bk; int bgi; float bv;
      bool pick0 = !f0 && (f1 || k0>k1 || (k0==k1 && ci0<ci1));
      if (pick0){ bk=k0; bgi=ci0; bv=cv0; }
      else if (!f1){ bk=k1; bgi=ci1; bv=cv1; }
      else { bk=-1.f; bgi=0x7fffffff; bv=0.f; }
      #pragma unroll
      for (int o=1;o<64;o<<=1){
        float ko=__shfl_xor(bk,o,64);
        int  gio=__shfl_xor(bgi,o,64);
        float vo=__shfl_xor(bv,o,64);
        if (ko>bk || (ko==bk && gio<bgi)){ bk=ko; bgi=gio; bv=vo; }
      }
      if (lane==0){ wout[orow+t]=bv; iout[orow+t]=bgi; }
      if (!f0 && bgi==ci0) f0=true;
      else if (!f1 && bgi==ci1) f1=true;
    }
  } else {
    unsigned long long cons = 0ull;
    float bk=-1.f, bval=0.f; int bj=0;
    #pragma unroll
    for (int j=0;j<64;j++){
      float k = fabsf(v[j]);
      if (k > bk){ bk=k; bj=j; bval=v[j]; }
    }
    for (int t=0;t<KK;t++){
      float k = bk; int gi = lane*64 + bj; float val = bval;
      #pragma unroll
      for (int o=1;o<64;o<<=1){
        float ko = __shfl_xor(k,o,64);
        int  gio = __shfl_xor(gi,o,64);
        float vo = __shfl_xor(val,o,64);
        if (ko > k || (ko == k && gio < gi)){ k=ko; gi=gio; val=vo; }
      }
      if (lane == 0){ wout[orow+t]=val; iout[orow+t]=gi; }
      if (lane == (gi>>6)){
        cons |= 1ull << (gi & 63);
        bk=-1.f; bj=0; bval=0.f;
        #pragma unroll
        for (int j=0;j<64;j++){
          if (!((cons>>j)&1ull)){
            float kk=fabsf(v[j]);
            if (kk>bk){ bk=kk; bj=j; bval=v[j]; }
          }
        }
      }
    }
  }
}

// ---- gather + signed-softmax weights + fused apply_delta ----
// v3: one WAVE per output row (4 rows/block), no LDS, no __syncthreads.
// Lanes 0..15 (replicated in all four 16-lane groups to avoid divergence)
// compute the 16 softmax weights with width-16 shuffle reduces; each lane
// then owns 4 contiguous d-elements and accumulates the 16 messages straight
// from global (each float4-per-lane load is a coalesced 1KB wave read of an
// L2/L3-resident row). Both LNs are pure wave shuffle reduces.
__global__ void __launch_bounds__(256) gather_kernel(
    const float* __restrict__ wbuf, const int* __restrict__ ibuf,
    const float* __restrict__ sv, long sv_bs,
    const float* __restrict__ nrm,
    const float* __restrict__ st, long st_bs,
    const float* __restrict__ base, int base_mod,
    const float* __restrict__ bg, const float* __restrict__ bb,
    const float* __restrict__ og, const float* __restrict__ ob,
    float* __restrict__ outv, float* __restrict__ ds)
{
  int t = threadIdx.x;
  int wid = t>>6, lane = t&63;
  long row = (long)blockIdx.x*4 + wid;
  int b = (int)(row >> 12);

  // ---- weights (all four 16-lane groups compute identical results) ----
  int kk = lane & 15;
  int si = ibuf[row*KK + kk];
  float w = wbuf[row*KK + kk];
  float aw = fabsf(w);
  float m = aw;
  #pragma unroll
  for (int o=1;o<16;o<<=1) m = fmaxf(m, __shfl_xor(m,o,64));
  float e = expf(aw - m);
  float Z = e;
  #pragma unroll
  for (int o=1;o<16;o<<=1) Z += __shfl_xor(Z,o,64);
  float sg = (w>0.f)?1.f:((w<0.f)?-1.f:0.f);
  float vv = sg*e/Z;
  if (st){
    float stv = st[(long)b*st_bs + si];
    vv *= fmaxf(stv,0.f) + log1pf(expf(-fabsf(stv)));   // softplus
  }
  float wsum = vv;
  #pragma unroll
  for (int o=1;o<16;o<<=1) wsum += __shfl_xor(wsum,o,64);
  if (lane==0) ds[row] = wsum;
  float wkp = vv * nrm[(long)b*NN + si];

  // ---- message accumulation: lane owns d = lane*4 .. lane*4+3 ----
  float4 acc = {0.f,0.f,0.f,0.f};
  const float* svb = sv + (long)b*sv_bs;
  #pragma unroll
  for (int k=0;k<KK;k++){
    int   sik = __shfl(si, k, 64);
    float wk  = __shfl(wkp, k, 64);
    float4 mq = *(const float4*)(svb + (long)sik*DD + lane*4);
    acc.x += wk*mq.x; acc.y += wk*mq.y; acc.z += wk*mq.z; acc.w += wk*mq.w;
  }

  if (!base){
    *(float4*)(outv + row*DD + lane*4) = acc;
    return;
  }
  const float* brow = base + (long)(base_mod ? (row % base_mod) : row)*DD;
  float4 x4 = *(const float4*)(brow + lane*4);
  if (bg){
    float s = x4.x+x4.y+x4.z+x4.w;
    float q = x4.x*x4.x+x4.y*x4.y+x4.z*x4.z+x4.w*x4.w;
    #pragma unroll
    for (int o=1;o<64;o<<=1){ s+=__shfl_xor(s,o,64); q+=__shfl_xor(q,o,64); }
    float mm=s*(1.f/DD), var=q*(1.f/DD)-mm*mm, rstd=rsqrtf(var+1e-5f);
    float4 g4 = *(const float4*)(bg + lane*4);
    float4 b4 = *(const float4*)(bb + lane*4);
    x4.x=(x4.x-mm)*rstd*g4.x+b4.x; x4.y=(x4.y-mm)*rstd*g4.y+b4.y;
    x4.z=(x4.z-mm)*rstd*g4.z+b4.z; x4.w=(x4.w-mm)*rstd*g4.w+b4.w;
  }
  x4.x+=acc.x; x4.y+=acc.y; x4.z+=acc.z; x4.w+=acc.w;
  {
    float s = x4.x+x4.y+x4.z+x4.w;
    float q = x4.x*x4.x+x4.y*x4.y+x4.z*x4.z+x4.w*x4.w;
    #pragma unroll
    for (int o=1;o<64;o<<=1){ s+=__shfl_xor(s,o,64); q+=__shfl_xor(q,o,64); }
    float mm=s*(1.f/DD), var=q*(1.f/DD)-mm*mm, rstd=rsqrtf(var+1e-5f);
    float4 g4 = *(const float4*)(og + lane*4);
    float4 b4 = *(const float4*)(ob + lane*4);
    float4 o4;
    o4.x=(x4.x-mm)*rstd*g4.x+b4.x; o4.y=(x4.y-mm)*rstd*g4.y+b4.y;
    o4.z=(x4.z-mm)*rstd*g4.z+b4.z; o4.w=(x4.w-mm)*rstd*g4.w+b4.w;
    *(float4*)(outv + row*DD + lane*4) = o4;
  }
}

extern "C" void kernel_launch(void* const* d_in, const int* in_sizes, int n_in,
                              void* d_out, int out_size, void* d_ws, size_t ws_size,
                              hipStream_t stream)
{
  const float* b_state    = (const float*)d_in[0];
  const float* b_val      = (const float*)d_in[1];
  const float* init_state = (const float*)d_in[2];
  const float* init_val   = (const float*)d_in[3];
  const float* U_bk = (const float*)d_in[4];
  const float* V_bk = (const float*)d_in[5];
  const float* U_kb = (const float*)d_in[6];
  const float* V_kb = (const float*)d_in[7];
  const float* U_p  = (const float*)d_in[8];
  const float* V_p  = (const float*)d_in[9];
  const float* kn_g = (const float*)d_in[10];
  const float* kn_b = (const float*)d_in[11];
  const float* bn_g = (const float*)d_in[12];
  const float* bn_b = (const float*)d_in[13];
  const float* pn_g = (const float*)d_in[14];
  const float* pn_b = (const float*)d_in[15];
  float* out = (float*)d_out;

  const long o_rstate = 0;
  const long o_rval   = (long)BB*NN;
  const long o_pstate = o_rval + (long)BB*NN*DD;
  const long o_pval   = o_pstate + (long)BB*NN;
  const long o_bds    = o_pval + (long)BB*NN*DD;
  const long o_bdv    = o_bds + (long)BB*NN;

  float* RVAL = out + o_rval;
  float* PVAL = out + o_pval;
  float* RST  = out + o_rstate;
  float* PST  = out + o_pstate;

  ushort* SPh = (ushort*)d_ws;                   // [B,N,R] bf16 hi
  ushort* SPl = SPh + (long)BB*NN*RR;
  ushort* DPh = SPl + (long)BB*NN*RR;
  ushort* DPl = DPh + (long)BB*NN*RR;
  float* WB   = (float*)(DPl + (long)BB*NN*RR);  // [B,N,K]
  int*   IB   = (int*)(WB + (long)BB*NN*KK);     // [B,N,K]
  float* KST  = (float*)(IB + (long)BB*NN*KK);   // [N]
  float* DS   = KST + NN;                        // [B,N]
  float* NV   = DS + (long)BB*NN;                // [B,N,D] normalized msgs
  float* NRM  = NV + (long)BB*NN*DD;             // [B,N] 1/(||row||+1e-6)
  float* SC   = NRM + (long)BB*NN;               // [B,cr,N] score chunk
  long fixed_bytes = (char*)SC - (char*)d_ws;
  int cr = 2048;
  while (cr > 128 && fixed_bytes + (long)BB*cr*NN*4 > (long)ws_size) cr >>= 1;

  auto run_scores = [&](const ushort* dh, const ushort* dl, long dpbs,
                        const ushort* sh, const ushort* sl){
    int nch = NN / cr;
    for (int c=0;c<nch;c++){
      score_mfma<<<dim3(NN/128, cr/128, BB), 256, 0, stream>>>(dh, dl, dpbs, sh, sl, SC, c*cr, cr);
      topk_kernel<<<dim3(BB*cr/4), 256, 0, stream>>>(SC, WB, IB, c*cr, cr);
    }
  };

  // ---- initialize_state: k_state (batch-independent) ----
  ssm_kernel<<<1,1024,0,stream>>>(init_state, 0, nullptr, 0, KST, 0);

  // ---- route_from_b: B -> K ----
  proj_ln_kernel<<<NN/TM,256,0,stream>>>(init_val, kn_g, kn_b, 2,
                                         V_bk, DPh, DPl, 0.125f, nullptr, nullptr, nullptr, 0.f,
                                         nullptr, nullptr);
  proj_ln_kernel<<<BB*NN/TM,256,0,stream>>>(b_val, nullptr, nullptr, 0,
                                            U_bk, SPh, SPl, 1.0f, nullptr, nullptr, nullptr, 0.f,
                                            nullptr, NRM);
  run_scores(DPh, DPl, 0, SPh, SPl);
  gather_kernel<<<BB*NN/4,256,0,stream>>>(WB, IB,
      b_val, (long)NN*DD, NRM,
      b_state, (long)NN,
      init_val, NN, kn_g, kn_b, kn_g, kn_b,
      RVAL, DS);
  ssm_kernel<<<BB,1024,0,stream>>>(KST, 0, DS, NN, RST, NN);

  // ---- propagate ----
  proj_ln_kernel<<<BB*NN/TM,256,0,stream>>>(RVAL, pn_g, pn_b, 1,
                                            U_p, SPh, SPl, 1.0f, V_p, DPh, DPl, 0.125f,
                                            NV, NRM);
  run_scores(DPh, DPl, (long)NN*RR, SPh, SPl);
  gather_kernel<<<BB*NN/4,256,0,stream>>>(WB, IB,
      NV, (long)NN*DD, NRM,
      nullptr, 0,
      RVAL, 0, nullptr, nullptr, kn_g, kn_b,
      PVAL, DS);
  ssm_kernel<<<BB,1024,0,stream>>>(RST, NN, DS, NN, PST, NN);

  // ---- transition_to_b: K -> B ----
  proj_ln_kernel<<<BB*NN/TM,256,0,stream>>>(PVAL, kn_g, kn_b, 1,
                                            U_kb, SPh, SPl, 1.0f, nullptr, nullptr, nullptr, 0.f,
                                            NV, NRM);
  proj_ln_kernel<<<BB*NN/TM,256,0,stream>>>(b_val, bn_g, bn_b, 1,
                                            V_kb, DPh, DPl, 0.125f, nullptr, nullptr, nullptr, 0.f,
                                            nullptr, nullptr);
  run_scores(DPh, DPl, (long)NN*RR, SPh, SPl);
  gather_kernel<<<BB*NN/4,256,0,stream>>>(WB, IB,
      NV, (long)NN*DD, NRM,
      PST, (long)NN,
      nullptr, 0, nullptr, nullptr, nullptr, nullptr,
      out + o_bdv, out + o_bds);
}